// Round 4
// baseline (744.011 us; speedup 1.0000x reference)
//
#include <hip/hip_runtime.h>
#include <stdint.h>

#define NN    6000
#define KNNC  10
#define MM    (NN * 2 * (KNNC + 1))   // 132000
#define DD    (2 * NN)                // 12000
#define LCH   3                       // hidden layers (LC-1)
#define BLK   256

#define NV        ((long long)DD * DD / 4)   // 36,000,000 float4s
#define FILLGRID  2048
#define MLPGRID   ((MM + BLK - 1) / BLK)     // 516

// Round-4 structure: three sequential kernels, each at its own roofline.
// R1-R3 post-mortems: every fill/MLP co-residency scheme (wave-specialized,
// wave-specialized+LDS-weights, block-specialized) lost 2x+ on the store
// stream, because the 64KB activation LDS caps residency at 2 blocks/CU and
// MLP blocks are ~100x longer than a fill block's share -> CUs go
// store-silent. Decomposed floors: fill 576MB ~95us (rocclr fill proves
// 6.15 TB/s), MLP ~21us aggregate VALU, scatter ~20us with NATIVE f32
// atomics. The R2 timing decomposition showed scatter ~126us: HIP
// atomicAdd(float*) emits a CAS retry loop (dependent load->cmpswap
// round-trips at HBM-miss latency); unsafeAtomicAdd emits
// global_atomic_add_f32 (fire-and-forget).

__global__ __launch_bounds__(BLK) void zero_fill(float* __restrict__ out) {
    // Pure streaming float4 stores, 0 LDS: clone of the 6.15 TB/s rocclr fill.
    const long long t0 = (long long)blockIdx.x * BLK + threadIdx.x;
    const long long stride = (long long)FILLGRID * BLK;
    float4 z = make_float4(0.f, 0.f, 0.f, 0.f);
    float4* outv = (float4*)out;
    for (long long i = t0; i < NV; i += stride) outv[i] = z;
}

__global__ __launch_bounds__(BLK) void mlp(
    const float* __restrict__ CK,    // [MM,3]
    const float* __restrict__ Win,   // [3,64]
    const float* __restrict__ bin,   // [64]
    const float* __restrict__ Whid,  // [3,64,64]
    const float* __restrict__ bhid,  // [3,64]
    const float* __restrict__ Wout,  // [64,4]
    const float* __restrict__ bout,  // [4]
    float* __restrict__ vals)        // [MM,2] (workspace)
{
    __shared__ float sH[64 * BLK];   // activations [k][tid], 64 KiB

    const int tid = threadIdx.x;
    const int m0  = blockIdx.x * BLK + tid;    // 0..132095
    const int m   = m0 < MM ? m0 : MM - 1;     // clamp loads, guard store

    const float x0 = CK[m * 3 + 0];
    const float x1 = CK[m * 3 + 1];
    const float x2 = CK[m * 3 + 2];

    float* __restrict__ hcol = sH + tid;       // h[k] lives at hcol[k*256]

    // Input layer 3 -> 64; weight/bias reads wave-uniform (broadcast).
#pragma unroll
    for (int j = 0; j < 64; j++) {
        float a = bin[j];
        a = fmaf(x0, Win[j],       a);
        a = fmaf(x1, Win[64 + j],  a);
        a = fmaf(x2, Win[128 + j], a);
        hcol[j * BLK] = fmaxf(a, 0.0f);        // static addr: ds_write_b32
    }

    // Hidden layers: g_j = sum_k W[k][j] * h_k (row-major W matches h @ W).
    // k-loop unrolled x8: uniform weight loads batch ahead of the FMAs;
    // g[] is fully statically indexed (registers); h lives in LDS [k][tid]
    // (2 lanes/bank alias = free) so no dynamic register indexing (no
    // scratch).
#pragma unroll 1
    for (int l = 0; l < LCH; l++) {
        const float4* __restrict__ W4 = (const float4*)(Whid + (l << 12));
        const float*  __restrict__ bh = bhid + (l << 6);
        float g[64];
#pragma unroll
        for (int j = 0; j < 64; j++) g[j] = bh[j];
#pragma unroll 8
        for (int k = 0; k < 64; k++) {
            const float hk = hcol[k * BLK];    // ds_read_b32
            const float4* __restrict__ Wk = W4 + (k << 4);   // row k: 16 float4s
#pragma unroll
            for (int j4 = 0; j4 < 16; j4++) {
                float4 w = Wk[j4];             // wave-uniform batch (s_load)
                g[j4 * 4 + 0] = fmaf(w.x, hk, g[j4 * 4 + 0]);
                g[j4 * 4 + 1] = fmaf(w.y, hk, g[j4 * 4 + 1]);
                g[j4 * 4 + 2] = fmaf(w.z, hk, g[j4 * 4 + 2]);
                g[j4 * 4 + 3] = fmaf(w.w, hk, g[j4 * 4 + 3]);
            }
        }
#pragma unroll
        for (int j = 0; j < 64; j++) hcol[j * BLK] = fmaxf(g[j], 0.0f);
    }

    // Output layer collapsed over mi: vals[:,mj] = C[:,mj] + C[:,mj+2]
    float v0 = bout[0] + bout[2];
    float v1 = bout[1] + bout[3];
#pragma unroll 8
    for (int k = 0; k < 64; k++) {
        float4 wo = *((const float4*)Wout + k);
        const float hk = hcol[k * BLK];
        v0 = fmaf(hk, wo.x + wo.z, v0);
        v1 = fmaf(hk, wo.y + wo.w, v1);
    }
    if (m0 < MM) *(float2*)(vals + 2 * m0) = make_float2(v0, v1);
}

__global__ __launch_bounds__(BLK) void scatter_add(
    const float* __restrict__ vals,   // [MM,2]
    const int* __restrict__ coo,      // [2,MM]
    float* __restrict__ out)          // [DD*DD]
{
    const int t = blockIdx.x * BLK + threadIdx.x;
    if (t >= MM) return;
    const int r2 = coo[t] * 2;        // row index * MODES
    const int c2 = coo[MM + t] * 2;   // col index * MODES
    const float2 v = *(const float2*)(vals + 2 * t);
    // mj=0: element (r2, c2); mj=1: element (r2+1, c2+1) = +DD+1 flat
    const long long f0 = (long long)r2 * DD + c2;
    // Native global_atomic_add_f32 (fire-and-forget), NOT the CAS retry
    // loop that plain atomicAdd(float*) lowers to.
    unsafeAtomicAdd(out + f0, v.x);
    unsafeAtomicAdd(out + f0 + DD + 1, v.y);
}

extern "C" void kernel_launch(void* const* d_in, const int* in_sizes, int n_in,
                              void* d_out, int out_size, void* d_ws, size_t ws_size,
                              hipStream_t stream) {
    const float* CK   = (const float*)d_in[0];
    const float* Win  = (const float*)d_in[1];
    const float* bin  = (const float*)d_in[2];
    const float* Whid = (const float*)d_in[3];
    const float* bhid = (const float*)d_in[4];
    const float* Wout = (const float*)d_in[5];
    const float* bout = (const float*)d_in[6];
    const int* coo    = (const int*)d_in[7];
    float* out        = (float*)d_out;
    float* vals       = (float*)d_ws;

    mlp<<<MLPGRID, BLK, 0, stream>>>(CK, Win, bin, Whid, bhid, Wout, bout, vals);
    zero_fill<<<FILLGRID, BLK, 0, stream>>>(out);
    scatter_add<<<MLPGRID, BLK, 0, stream>>>(vals, coo, out);
}